// Round 1
// 82.930 us; speedup vs baseline: 1.0032x; 1.0032x over previous
//
#include <hip/hip_runtime.h>

// out[b] = log( p0*(p1 + p2 - 2*p1*p2) + (1-p0)*p1*p2 ),  pi = exp(lp_i)
// Mathematically identical to the log-space DAG in the reference; all
// intermediates are in [~0.005, 1) so probability-space is fp32-safe.
__device__ __forceinline__ float eval_pc(float lp0, float lp1, float lp2) {
    float p0 = __expf(lp0);
    float p1 = __expf(lp1);
    float p2 = __expf(lp2);
    float p1p2  = p1 * p2;
    float inner = p1 + p2 - 2.0f * p1p2;          // p1(1-p2) + (1-p1)p2
    float tot   = fmaf(p0, inner, (1.0f - p0) * p1p2);
    return __logf(tot);
}

// Block-cooperative version: 256 threads stage 768 contiguous float4
// (= 1024 batch elements = 12 KB) into LDS with perfectly coalesced
// 16 B/lane loads (dense 4 KB span per wave-instruction, vs the previous
// 48 B-stride pattern that scattered each load over a 3 KB span).
// Each thread then pulls its 12 floats from LDS (3x ds_read_b128; stride-12
// words -> 8-way bank conflict, ~1 us total at this wave count) and computes
// 4 outputs. Output store is unchanged (already dense float4).
__global__ __launch_bounds__(256) void pc_eval_lds(const float4* __restrict__ in,
                                                   float4* __restrict__ out) {
    __shared__ float4 lds4[768];                 // 12 KB
    const int tid = threadIdx.x;
    const int base = blockIdx.x * 768;           // < 3.1M, int-safe
    lds4[tid      ] = in[base + tid      ];
    lds4[tid + 256] = in[base + tid + 256];
    lds4[tid + 512] = in[base + tid + 512];
    __syncthreads();

    // 48-byte offset from a 16B-aligned base -> 16B aligned, 3x b128 reads.
    const float4* my4 = (const float4*)((const float*)lds4 + 12 * tid);
    float4 a = my4[0];
    float4 b = my4[1];
    float4 c = my4[2];

    float4 o;
    o.x = eval_pc(a.x, a.y, a.z);
    o.y = eval_pc(a.w, b.x, b.y);
    o.z = eval_pc(b.z, b.w, c.x);
    o.w = eval_pc(c.y, c.z, c.w);
    out[blockIdx.x * 256 + tid] = o;
}

// Generic fallback (48B-stride float4 path) for sizes not divisible by 1024.
__global__ __launch_bounds__(256) void pc_eval_vec4(const float4* __restrict__ in,
                                                    float4* __restrict__ out,
                                                    int n4) {
    int t = blockIdx.x * blockDim.x + threadIdx.x;
    if (t >= n4) return;
    float4 a = in[3 * t + 0];
    float4 b = in[3 * t + 1];
    float4 c = in[3 * t + 2];
    float4 o;
    o.x = eval_pc(a.x, a.y, a.z);
    o.y = eval_pc(a.w, b.x, b.y);
    o.z = eval_pc(b.z, b.w, c.x);
    o.w = eval_pc(c.y, c.z, c.w);
    out[t] = o;
}

// Scalar tail (not used at B = 2^22, kept for generality).
__global__ void pc_eval_tail(const float* __restrict__ in, float* __restrict__ out,
                             int start, int n) {
    int b = start + blockIdx.x * blockDim.x + threadIdx.x;
    if (b >= n) return;
    out[b] = eval_pc(in[3 * b + 0], in[3 * b + 1], in[3 * b + 2]);
}

extern "C" void kernel_launch(void* const* d_in, const int* in_sizes, int n_in,
                              void* d_out, int out_size, void* d_ws, size_t ws_size,
                              hipStream_t stream) {
    const float* lp = (const float*)d_in[0];
    float* out = (float*)d_out;
    int B = in_sizes[0] / 3;                     // (B, 3) float32

    const int block = 256;
    const int elems_per_block = 1024;            // 256 threads x 4 elements

    int nfull = B / elems_per_block;             // B = 2^22 -> 4096, exact
    if (nfull > 0) {
        pc_eval_lds<<<nfull, block, 0, stream>>>((const float4*)lp, (float4*)out);
    }
    int done = nfull * elems_per_block;
    if (done < B) {
        int rem = B - done;
        int rem4 = rem / 4;
        if (rem4 > 0) {
            pc_eval_vec4<<<(rem4 + block - 1) / block, block, 0, stream>>>(
                (const float4*)(lp + (size_t)done * 3),
                (float4*)(out + done), rem4);
        }
        int done2 = done + rem4 * 4;
        if (done2 < B) {
            int rem2 = B - done2;
            pc_eval_tail<<<(rem2 + block - 1) / block, block, 0, stream>>>(
                lp, out, done2, B);
        }
    }
}